// Round 1
// baseline (3254.579 us; speedup 1.0000x reference)
//
#include <hip/hip_runtime.h>
#include <stdint.h>

// Problem constants (fixed by setup_inputs)
constexpr int B   = 2;
constexpr int T   = 2048;
constexpr int D   = 2048;
constexpr int H   = 32;
constexpr int KVH = 8;
constexpr int HD  = 64;          // head dim
constexpr int R   = B * T;       // 4096 rows
constexpr int OKV = KVH * HD;    // 512

__device__ inline int dot4(int a, int b, int c) {
#if __has_builtin(__builtin_amdgcn_sdot4)
    return __builtin_amdgcn_sdot4(a, b, c, false);
#else
    c += (int)(int8_t)(a & 0xff)         * (int)(int8_t)(b & 0xff);
    c += (int)(int8_t)((a >> 8) & 0xff)  * (int)(int8_t)((b >> 8) & 0xff);
    c += (int)(int8_t)((a >> 16) & 0xff) * (int)(int8_t)((b >> 16) & 0xff);
    c += (int)(int8_t)(a >> 24)          * (int)(int8_t)(b >> 24);
    return c;
#endif
}

// ---------------- weight scale: mean(|w|) ----------------
__global__ void absmean_kernel(const float* __restrict__ w, int n, double* __restrict__ sum) {
    __shared__ float red[256];
    int tid = threadIdx.x;
    float s = 0.f;
    for (int i = blockIdx.x * 256 + tid; i < n; i += gridDim.x * 256)
        s += fabsf(w[i]);
    red[tid] = s;
    __syncthreads();
    for (int st = 128; st > 0; st >>= 1) {
        if (tid < st) red[tid] += red[tid + st];
        __syncthreads();
    }
    if (tid == 0) atomicAdd(sum, (double)red[0]);
}

__global__ void finalize_ws_kernel(const double* __restrict__ sums, float* __restrict__ wsc,
                                   int n0, int n1, int n2, int n3) {
    int i = threadIdx.x;
    int ns[4] = {n0, n1, n2, n3};
    if (i < 4) {
        float m = (float)(sums[i] / (double)ns[i]);
        wsc[i] = fmaxf(m, 1e-5f);
    }
}

// ---------------- ternary weight quantization ----------------
__global__ void quantw_kernel(const float* __restrict__ w, int8_t* __restrict__ w8, int n,
                              const float* __restrict__ wsc, int wi) {
    float ws = wsc[wi];
    for (int i = blockIdx.x * 256 + threadIdx.x; i < n; i += gridDim.x * 256) {
        float q = rintf(w[i] / ws);
        q = fminf(fmaxf(q, -1.f), 1.f);
        w8[i] = (int8_t)q;
    }
}

// ---------------- rmsnorm + absmax int8 activation quant (one block per row) --------
__global__ void rmsq_kernel(const float* __restrict__ X, const float* __restrict__ g,
                            int8_t* __restrict__ Xq, float* __restrict__ xs_out) {
    __shared__ float red[256];
    int row = blockIdx.x;
    int tid = threadIdx.x;
    const float* xr = X + (size_t)row * D;

    float ss = 0.f;
    for (int i = tid; i < D; i += 256) { float v = xr[i]; ss += v * v; }
    red[tid] = ss;
    __syncthreads();
    for (int st = 128; st > 0; st >>= 1) {
        if (tid < st) red[tid] += red[tid + st];
        __syncthreads();
    }
    float ms = red[0] / (float)D;
    float rstd = 1.0f / sqrtf(ms + 1e-6f);
    __syncthreads();

    float amax = 0.f;
    for (int i = tid; i < D; i += 256) {
        float xn = xr[i] * rstd * g[i];
        amax = fmaxf(amax, fabsf(xn));
    }
    red[tid] = amax;
    __syncthreads();
    for (int st = 128; st > 0; st >>= 1) {
        if (tid < st) red[tid] = fmaxf(red[tid], red[tid + st]);
        __syncthreads();
    }
    float xs = fmaxf(red[0], 1e-5f);

    for (int i = tid; i < D; i += 256) {
        float xn = xr[i] * rstd * g[i];
        float q = rintf(xn * 127.0f / xs);
        q = fminf(fmaxf(q, -128.f), 127.f);
        Xq[(size_t)row * D + i] = (int8_t)q;
    }
    if (tid == 0) xs_out[row] = xs;
}

// ---------------- int8 GEMM: out[r,o] = dot(Xq[r,:], W8[o,:]) * wsc * xs[r] / 127 ----
// 32x32 tile per block (16x16 threads, 2x2 outputs/thread), K-tile = 32 bytes (8 ints)
__global__ __launch_bounds__(256) void gemm_i8_kernel(const int8_t* __restrict__ Xq,
                                                      const int8_t* __restrict__ W8,
                                                      float* __restrict__ out,
                                                      const float* __restrict__ xs,
                                                      const float* __restrict__ wsc, int wi,
                                                      int O) {
    __shared__ int As[32][9];
    __shared__ int Bs[32][9];
    const int Dw = D / 4;  // ints per row = 512
    int tx = threadIdx.x, ty = threadIdx.y;
    int tid = ty * 16 + tx;
    int row0 = blockIdx.y * 32;
    int col0 = blockIdx.x * 32;
    const int* X4 = (const int*)Xq;
    const int* W4 = (const int*)W8;
    int lr = tid >> 3;      // 0..31
    int lc = tid & 7;       // 0..7
    int acc00 = 0, acc01 = 0, acc10 = 0, acc11 = 0;

    for (int k0 = 0; k0 < Dw; k0 += 8) {
        As[lr][lc] = X4[(size_t)(row0 + lr) * Dw + k0 + lc];
        Bs[lr][lc] = W4[(size_t)(col0 + lr) * Dw + k0 + lc];
        __syncthreads();
#pragma unroll
        for (int kk = 0; kk < 8; kk++) {
            int a0 = As[2 * ty][kk],     a1 = As[2 * ty + 1][kk];
            int b0 = Bs[2 * tx][kk],     b1 = Bs[2 * tx + 1][kk];
            acc00 = dot4(a0, b0, acc00);
            acc01 = dot4(a0, b1, acc01);
            acc10 = dot4(a1, b0, acc10);
            acc11 = dot4(a1, b1, acc11);
        }
        __syncthreads();
    }
    int r0 = row0 + 2 * ty, r1 = r0 + 1;
    int c0 = col0 + 2 * tx, c1 = c0 + 1;
    float w = wsc[wi];
    float f0 = w * xs[r0] / 127.0f;
    float f1 = w * xs[r1] / 127.0f;
    out[(size_t)r0 * O + c0] = acc00 * f0;
    out[(size_t)r0 * O + c1] = acc01 * f0;
    out[(size_t)r1 * O + c0] = acc10 * f1;
    out[(size_t)r1 * O + c1] = acc11 * f1;
}

// ---------------- RoPE in place on [B,T,NH*HD] ----------------
__global__ void rope_kernel(float* __restrict__ x, const float* __restrict__ cs,
                            const float* __restrict__ sn, int NH, int total) {
    int idx = blockIdx.x * 256 + threadIdx.x;
    if (idx >= total) return;
    int i = idx & 31;                 // 0..31
    int h = (idx >> 5) % NH;
    int bt = idx / (32 * NH);         // b*T + t
    int t = bt % T;
    size_t base = ((size_t)bt * NH + h) * HD;
    float x0 = x[base + i], x1 = x[base + i + 32];
    float c0 = cs[t * HD + i], c1 = cs[t * HD + i + 32];
    float s0 = sn[t * HD + i], s1 = sn[t * HD + i + 32];
    x[base + i]      = x0 * c0 - x1 * s0;
    x[base + i + 32] = x1 * c1 + x0 * s1;
}

// ---------------- causal GQA flash attention ----------------
// grid (T/4, H, B), block 256 = 4 waves; wave w handles query row t4*4+w
__global__ __launch_bounds__(256) void attn_kernel(const float* __restrict__ q,
                                                   const float* __restrict__ k,
                                                   const float* __restrict__ v,
                                                   float* __restrict__ out) {
    __shared__ float qs[4][64];
    __shared__ float Ks[64][65];
    __shared__ float ps[4][64];

    int tid  = threadIdx.x;
    int lane = tid & 63;
    int wid  = tid >> 6;
    int t4 = blockIdx.x, h = blockIdx.y, b = blockIdx.z;
    int qt = t4 * 4 + wid;
    int kvh = h >> 2;  // n_rep = 4 (repeat_interleave)
    const float scale = 0.125f;  // 1/sqrt(64)

    qs[wid][lane] = q[(size_t)(b * T + qt) * (H * HD) + h * HD + lane];

    float acc = 0.f, m = -INFINITY, l = 0.f;
    int kmax = t4 * 4 + 3;

    int ldr = tid >> 2;          // 0..63 row
    int ldc = tid & 3;           // float4 group

    for (int t0 = 0; t0 <= kmax; t0 += 64) {
        __syncthreads();
        // load K chunk [64 keys][64 dims]
        {
            const float4* src = (const float4*)(k + (size_t)(b * T + t0 + ldr) * OKV + kvh * HD);
#pragma unroll
            for (int it = 0; it < 4; it++) {
                float4 val = src[ldc + it * 4];
                int e = (ldc + it * 4) * 4;
                Ks[ldr][e + 0] = val.x; Ks[ldr][e + 1] = val.y;
                Ks[ldr][e + 2] = val.z; Ks[ldr][e + 3] = val.w;
            }
        }
        __syncthreads();

        float p = 0.f;
        bool active = (t0 <= qt);
        if (active) {
            int kt = t0 + lane;
            float s = 0.f;
#pragma unroll
            for (int d2 = 0; d2 < 64; d2++) s += qs[wid][d2] * Ks[lane][d2];
            s *= scale;
            if (kt > qt) s = -INFINITY;
            // wave max
            float mc = s;
            for (int o = 32; o > 0; o >>= 1) mc = fmaxf(mc, __shfl_xor(mc, o));
            float mnew = fmaxf(m, mc);
            float corr = expf(m - mnew);  // m=-inf -> 0
            p = expf(s - mnew);           // s=-inf -> 0
            float psum = p;
            for (int o = 32; o > 0; o >>= 1) psum += __shfl_xor(psum, o);
            l = l * corr + psum;
            acc *= corr;
            m = mnew;
        }
        ps[wid][lane] = p;
        __syncthreads();
        // load V chunk over Ks
        {
            const float4* src = (const float4*)(v + (size_t)(b * T + t0 + ldr) * OKV + kvh * HD);
#pragma unroll
            for (int it = 0; it < 4; it++) {
                float4 val = src[ldc + it * 4];
                int e = (ldc + it * 4) * 4;
                Ks[ldr][e + 0] = val.x; Ks[ldr][e + 1] = val.y;
                Ks[ldr][e + 2] = val.z; Ks[ldr][e + 3] = val.w;
            }
        }
        __syncthreads();
        if (active) {
#pragma unroll
            for (int j = 0; j < 64; j++) acc += ps[wid][j] * Ks[j][lane];
        }
    }
    out[(size_t)(b * T + qt) * (H * HD) + h * HD + lane] = acc / l;
}

// ---------------- launch ----------------
extern "C" void kernel_launch(void* const* d_in, const int* in_sizes, int n_in,
                              void* d_out, int out_size, void* d_ws, size_t ws_size,
                              hipStream_t stream) {
    const float* x   = (const float*)d_in[0];
    const float* cs  = (const float*)d_in[1];
    const float* sn  = (const float*)d_in[2];
    const float* wq  = (const float*)d_in[3];
    const float* wk  = (const float*)d_in[4];
    const float* wv  = (const float*)d_in[5];
    const float* wo  = (const float*)d_in[6];
    const float* gq  = (const float*)d_in[7];
    const float* gk  = (const float*)d_in[8];
    const float* gv  = (const float*)d_in[9];
    const float* go  = (const float*)d_in[10];
    float* out = (float*)d_out;

    uint8_t* w = (uint8_t*)d_ws;
    double* wsum  = (double*)w;                 // 4 doubles
    float* wscale = (float*)(w + 64);           // 4 floats
    float* xs     = (float*)(w + 256);          // 4 * R floats
    size_t off = 256 + 4 * (size_t)R * 4;       // 256 + 64KB
    int8_t* Wq8 = (int8_t*)(w + off); off += (size_t)D * D;
    int8_t* Wk8 = (int8_t*)(w + off); off += (size_t)OKV * D;
    int8_t* Wv8 = (int8_t*)(w + off); off += (size_t)OKV * D;
    int8_t* Wo8 = (int8_t*)(w + off); off += (size_t)D * D;
    int8_t* Xq_q = (int8_t*)(w + off); off += (size_t)R * D;
    int8_t* Xq_k = (int8_t*)(w + off); off += (size_t)R * D;
    int8_t* Xq_v = (int8_t*)(w + off); off += (size_t)R * D;
    float* qb = (float*)(w + off); off += (size_t)R * D * 4;
    float* kb = (float*)(w + off); off += (size_t)R * OKV * 4;
    float* vb = (float*)(w + off); off += (size_t)R * OKV * 4;
    float* ab = (float*)(w + off); off += (size_t)R * D * 4;
    int8_t* Aq8 = Xq_q;  // reuse (dead after projection GEMMs)

    hipMemsetAsync(wsum, 0, 64, stream);

    absmean_kernel<<<512, 256, 0, stream>>>(wq, D * D, wsum + 0);
    absmean_kernel<<<512, 256, 0, stream>>>(wk, OKV * D, wsum + 1);
    absmean_kernel<<<512, 256, 0, stream>>>(wv, OKV * D, wsum + 2);
    absmean_kernel<<<512, 256, 0, stream>>>(wo, D * D, wsum + 3);
    finalize_ws_kernel<<<1, 64, 0, stream>>>(wsum, wscale, D * D, OKV * D, OKV * D, D * D);

    quantw_kernel<<<4096, 256, 0, stream>>>(wq, Wq8, D * D, wscale, 0);
    quantw_kernel<<<1024, 256, 0, stream>>>(wk, Wk8, OKV * D, wscale, 1);
    quantw_kernel<<<1024, 256, 0, stream>>>(wv, Wv8, OKV * D, wscale, 2);
    quantw_kernel<<<4096, 256, 0, stream>>>(wo, Wo8, D * D, wscale, 3);

    rmsq_kernel<<<R, 256, 0, stream>>>(x, gq, Xq_q, xs + 0 * R);
    rmsq_kernel<<<R, 256, 0, stream>>>(x, gk, Xq_k, xs + 1 * R);
    rmsq_kernel<<<R, 256, 0, stream>>>(x, gv, Xq_v, xs + 2 * R);

    gemm_i8_kernel<<<dim3(D / 32, R / 32), dim3(16, 16), 0, stream>>>(Xq_q, Wq8, qb, xs + 0 * R, wscale, 0, D);
    gemm_i8_kernel<<<dim3(OKV / 32, R / 32), dim3(16, 16), 0, stream>>>(Xq_k, Wk8, kb, xs + 1 * R, wscale, 1, OKV);
    gemm_i8_kernel<<<dim3(OKV / 32, R / 32), dim3(16, 16), 0, stream>>>(Xq_v, Wv8, vb, xs + 2 * R, wscale, 2, OKV);

    {
        int totq = R * H * 32;
        rope_kernel<<<(totq + 255) / 256, 256, 0, stream>>>(qb, cs, sn, H, totq);
        int totk = R * KVH * 32;
        rope_kernel<<<(totk + 255) / 256, 256, 0, stream>>>(kb, cs, sn, KVH, totk);
    }

    attn_kernel<<<dim3(T / 4, H, B), 256, 0, stream>>>(qb, kb, vb, ab);

    rmsq_kernel<<<R, 256, 0, stream>>>(ab, go, Aq8, xs + 3 * R);
    gemm_i8_kernel<<<dim3(D / 32, R / 32), dim3(16, 16), 0, stream>>>(Aq8, Wo8, out, xs + 3 * R, wscale, 3, D);
}

// Round 2
// 1167.540 us; speedup vs baseline: 2.7876x; 2.7876x over previous
//
#include <hip/hip_runtime.h>
#include <stdint.h>

// Problem constants (fixed by setup_inputs)
constexpr int B   = 2;
constexpr int T   = 2048;
constexpr int D   = 2048;
constexpr int H   = 32;
constexpr int KVH = 8;
constexpr int HD  = 64;          // head dim
constexpr int R   = B * T;       // 4096 rows
constexpr int OKV = KVH * HD;    // 512

using bf16x8 = __attribute__((ext_vector_type(8))) __bf16;
using f32x4  = __attribute__((ext_vector_type(4))) float;

__device__ inline uint16_t f2bf(float f) {
    uint32_t u = __float_as_uint(f);
    u += 0x7fff + ((u >> 16) & 1);   // RNE
    return (uint16_t)(u >> 16);
}

__device__ inline int dot4(int a, int b, int c) {
#if __has_builtin(__builtin_amdgcn_sdot4)
    return __builtin_amdgcn_sdot4(a, b, c, false);
#else
    c += (int)(int8_t)(a & 0xff)         * (int)(int8_t)(b & 0xff);
    c += (int)(int8_t)((a >> 8) & 0xff)  * (int)(int8_t)((b >> 8) & 0xff);
    c += (int)(int8_t)((a >> 16) & 0xff) * (int)(int8_t)((b >> 16) & 0xff);
    c += (int)(int8_t)(a >> 24)          * (int)(int8_t)(b >> 24);
    return c;
#endif
}

// ---------------- weight scale: mean(|w|) ----------------
__global__ void absmean_kernel(const float* __restrict__ w, int n, double* __restrict__ sum) {
    __shared__ float red[256];
    int tid = threadIdx.x;
    float s = 0.f;
    for (int i = blockIdx.x * 256 + tid; i < n; i += gridDim.x * 256)
        s += fabsf(w[i]);
    red[tid] = s;
    __syncthreads();
    for (int st = 128; st > 0; st >>= 1) {
        if (tid < st) red[tid] += red[tid + st];
        __syncthreads();
    }
    if (tid == 0) atomicAdd(sum, (double)red[0]);
}

__global__ void finalize_ws_kernel(const double* __restrict__ sums, float* __restrict__ wsc,
                                   int n0, int n1, int n2, int n3) {
    int i = threadIdx.x;
    int ns[4] = {n0, n1, n2, n3};
    if (i < 4) {
        float m = (float)(sums[i] / (double)ns[i]);
        wsc[i] = fmaxf(m, 1e-5f);
    }
}

// ---------------- ternary weight quantization ----------------
__global__ void quantw_kernel(const float* __restrict__ w, int8_t* __restrict__ w8, int n,
                              const float* __restrict__ wsc, int wi) {
    float ws = wsc[wi];
    for (int i = blockIdx.x * 256 + threadIdx.x; i < n; i += gridDim.x * 256) {
        float q = rintf(w[i] / ws);
        q = fminf(fmaxf(q, -1.f), 1.f);
        w8[i] = (int8_t)q;
    }
}

// ---------------- rmsnorm + absmax int8 activation quant (one block per row) --------
__global__ void rmsq_kernel(const float* __restrict__ X, const float* __restrict__ g,
                            int8_t* __restrict__ Xq, float* __restrict__ xs_out) {
    __shared__ float red[256];
    int row = blockIdx.x;
    int tid = threadIdx.x;
    const float* xr = X + (size_t)row * D;

    float ss = 0.f;
    for (int i = tid; i < D; i += 256) { float v = xr[i]; ss += v * v; }
    red[tid] = ss;
    __syncthreads();
    for (int st = 128; st > 0; st >>= 1) {
        if (tid < st) red[tid] += red[tid + st];
        __syncthreads();
    }
    float ms = red[0] / (float)D;
    float rstd = 1.0f / sqrtf(ms + 1e-6f);
    __syncthreads();

    float amax = 0.f;
    for (int i = tid; i < D; i += 256) {
        float xn = xr[i] * rstd * g[i];
        amax = fmaxf(amax, fabsf(xn));
    }
    red[tid] = amax;
    __syncthreads();
    for (int st = 128; st > 0; st >>= 1) {
        if (tid < st) red[tid] = fmaxf(red[tid], red[tid + st]);
        __syncthreads();
    }
    float xs = fmaxf(red[0], 1e-5f);

    for (int i = tid; i < D; i += 256) {
        float xn = xr[i] * rstd * g[i];
        float q = rintf(xn * 127.0f / xs);
        q = fminf(fmaxf(q, -128.f), 127.f);
        Xq[(size_t)row * D + i] = (int8_t)q;
    }
    if (tid == 0) xs_out[row] = xs;
}

// ---------------- int8 GEMM (dot4) ----------------
__global__ __launch_bounds__(256) void gemm_i8_kernel(const int8_t* __restrict__ Xq,
                                                      const int8_t* __restrict__ W8,
                                                      float* __restrict__ out,
                                                      const float* __restrict__ xs,
                                                      const float* __restrict__ wsc, int wi,
                                                      int O) {
    __shared__ int As[32][9];
    __shared__ int Bs[32][9];
    const int Dw = D / 4;  // ints per row = 512
    int tx = threadIdx.x, ty = threadIdx.y;
    int tid = ty * 16 + tx;
    int row0 = blockIdx.y * 32;
    int col0 = blockIdx.x * 32;
    const int* X4 = (const int*)Xq;
    const int* W4 = (const int*)W8;
    int lr = tid >> 3;
    int lc = tid & 7;
    int acc00 = 0, acc01 = 0, acc10 = 0, acc11 = 0;

    for (int k0 = 0; k0 < Dw; k0 += 8) {
        As[lr][lc] = X4[(size_t)(row0 + lr) * Dw + k0 + lc];
        Bs[lr][lc] = W4[(size_t)(col0 + lr) * Dw + k0 + lc];
        __syncthreads();
#pragma unroll
        for (int kk = 0; kk < 8; kk++) {
            int a0 = As[2 * ty][kk],     a1 = As[2 * ty + 1][kk];
            int b0 = Bs[2 * tx][kk],     b1 = Bs[2 * tx + 1][kk];
            acc00 = dot4(a0, b0, acc00);
            acc01 = dot4(a0, b1, acc01);
            acc10 = dot4(a1, b0, acc10);
            acc11 = dot4(a1, b1, acc11);
        }
        __syncthreads();
    }
    int r0 = row0 + 2 * ty, r1 = r0 + 1;
    int c0 = col0 + 2 * tx, c1 = c0 + 1;
    float w = wsc[wi];
    float f0 = w * xs[r0] / 127.0f;
    float f1 = w * xs[r1] / 127.0f;
    out[(size_t)r0 * O + c0] = acc00 * f0;
    out[(size_t)r0 * O + c1] = acc01 * f0;
    out[(size_t)r1 * O + c0] = acc10 * f1;
    out[(size_t)r1 * O + c1] = acc11 * f1;
}

// ---------------- RoPE fp32 -> bf16 ----------------
__global__ void rope_bf16_kernel(const float* __restrict__ x, const float* __restrict__ cs,
                                 const float* __restrict__ sn, uint16_t* __restrict__ o,
                                 int NH, int total) {
    int idx = blockIdx.x * 256 + threadIdx.x;
    if (idx >= total) return;
    int i = idx & 31;                 // 0..31
    int hh = (idx >> 5) % NH;
    int bt = idx / (32 * NH);         // b*T + t
    int t = bt % T;
    size_t base = ((size_t)bt * NH + hh) * HD;
    float x0 = x[base + i], x1 = x[base + i + 32];
    float c0 = cs[t * HD + i], c1 = cs[t * HD + i + 32];
    float s0 = sn[t * HD + i], s1 = sn[t * HD + i + 32];
    o[base + i]      = f2bf(x0 * c0 - x1 * s0);
    o[base + i + 32] = f2bf(x1 * c1 + x0 * s1);
}

__global__ void cvt_bf16_kernel(const float* __restrict__ x, uint16_t* __restrict__ o, int ntot) {
    int i = blockIdx.x * 256 + threadIdx.x;
    if (i < ntot) o[i] = f2bf(x[i]);
}

// ---------------- MFMA flash attention (S^T = K Q^T, O^T = V^T P^T) ----------------
// grid (T/64, H, B), 256 threads = 4 waves; wave w handles q rows [q0+16w, q0+16w+16)
__global__ __launch_bounds__(256) void attn_mfma_kernel(const uint16_t* __restrict__ qh,
                                                        const uint16_t* __restrict__ kh,
                                                        const uint16_t* __restrict__ vh,
                                                        float* __restrict__ out) {
    __shared__ uint16_t Ks[64 * 72];      // [key][d], stride 72
    __shared__ uint16_t Vt[64 * 72];      // [d][key^swizzle], stride 72
    __shared__ uint16_t Pt[4][64 * 18];   // per-wave P^T [key][q], stride 18

    const int tid  = threadIdx.x;
    const int lane = tid & 63;
    const int wv   = tid >> 6;
    const int bx = blockIdx.x, h = blockIdx.y, b = blockIdx.z;
    const int q0 = bx * 64;
    const int kvh = h >> 2;               // n_rep = 4
    const int n = lane & 15, quad = lane >> 4;
    const int qg = q0 + wv * 16 + n;      // this lane's q column (global row idx)

    // Q B-frags: B[k=d][n=q] = Q[q][d], lane holds d = ks*32 + quad*8 + j
    bf16x8 qf[2];
    {
        const uint16_t* qp = qh + (size_t)(b * T + qg) * D + h * HD + quad * 8;
        qf[0] = *(const bf16x8*)(qp);
        qf[1] = *(const bf16x8*)(qp + 32);
    }

    f32x4 o[4] = {{0.f,0.f,0.f,0.f},{0.f,0.f,0.f,0.f},{0.f,0.f,0.f,0.f},{0.f,0.f,0.f,0.f}};
    float m = -INFINITY, l = 0.f;

    const int nchunks = bx + 1;
    const int sr = tid >> 2;            // staging key row 0..63
    const int sc = (tid & 3) * 16;      // staging col base

    for (int ch = 0; ch < nchunks; ch++) {
        const int t0 = ch * 64;
        __syncthreads();
        {
            const uint16_t* ksrc = kh + (size_t)(b * T + t0 + sr) * OKV + kvh * HD + sc;
            *(uint4*)&Ks[sr * 72 + sc]     = *(const uint4*)(ksrc);
            *(uint4*)&Ks[sr * 72 + sc + 8] = *(const uint4*)(ksrc + 8);
            const uint16_t* vsrc = vh + (size_t)(b * T + t0 + sr) * OKV + kvh * HD + sc;
#pragma unroll
            for (int half = 0; half < 2; half++) {
                int d0 = sc + half * 8;
                uint4 raw = *(const uint4*)(vsrc + half * 8);
                const uint16_t* pr = (const uint16_t*)&raw;
                int kpos = (sr & 7) + 8 * ((sr >> 3) ^ (d0 >> 3));
#pragma unroll
                for (int j = 0; j < 8; j++)
                    Vt[(d0 + j) * 72 + kpos] = pr[j];
            }
        }
        __syncthreads();

        if (t0 <= q0 + wv * 16 + 15) {
            // S^T[key][q]: A = K (m=key), B = Q^T
            f32x4 s[4] = {{0.f,0.f,0.f,0.f},{0.f,0.f,0.f,0.f},{0.f,0.f,0.f,0.f},{0.f,0.f,0.f,0.f}};
#pragma unroll
            for (int ks = 0; ks < 2; ks++) {
#pragma unroll
                for (int mt = 0; mt < 4; mt++) {
                    bf16x8 kf = *(const bf16x8*)&Ks[(mt * 16 + n) * 72 + ks * 32 + quad * 8];
                    s[mt] = __builtin_amdgcn_mfma_f32_16x16x32_bf16(kf, qf[ks], s[mt], 0, 0, 0);
                }
            }
            // scale + causal mask + per-q max (keys live on quads: shfl 16, 32)
            float mloc = -INFINITY;
#pragma unroll
            for (int mt = 0; mt < 4; mt++) {
#pragma unroll
                for (int r2 = 0; r2 < 4; r2++) {
                    int kg = t0 + mt * 16 + quad * 4 + r2;
                    float sv = s[mt][r2] * 0.125f;
                    sv = (kg > qg) ? -INFINITY : sv;
                    s[mt][r2] = sv;
                    mloc = fmaxf(mloc, sv);
                }
            }
            mloc = fmaxf(mloc, __shfl_xor(mloc, 16));
            mloc = fmaxf(mloc, __shfl_xor(mloc, 32));
            float mnew = fmaxf(m, mloc);
            float corr = __expf(m - mnew);   // first chunk: exp(-inf)=0
            float ls = 0.f;
#pragma unroll
            for (int mt = 0; mt < 4; mt++) {
#pragma unroll
                for (int r2 = 0; r2 < 4; r2++) {
                    float p = __expf(s[mt][r2] - mnew);
                    ls += p;
                    Pt[wv][(mt * 16 + quad * 4 + r2) * 18 + n] = f2bf(p);
                }
            }
            ls += __shfl_xor(ls, 16);
            ls += __shfl_xor(ls, 32);
            l = l * corr + ls;
            m = mnew;
#pragma unroll
            for (int mt = 0; mt < 4; mt++)
#pragma unroll
                for (int r2 = 0; r2 < 4; r2++) o[mt][r2] *= corr;

            // O^T += V^T P^T : A = V^T (m=dim, k=key) from swizzled Vt, B = P^T
#pragma unroll
            for (int ks = 0; ks < 2; ks++) {
                union { bf16x8 v; uint16_t u[8]; } pf;
#pragma unroll
                for (int j = 0; j < 8; j++)
                    pf.u[j] = Pt[wv][(ks * 32 + quad * 8 + j) * 18 + n];
#pragma unroll
                for (int mt = 0; mt < 4; mt++) {
                    int d = mt * 16 + n;
                    bf16x8 vf = *(const bf16x8*)&Vt[d * 72 + 8 * ((ks * 4 + quad) ^ ((d >> 3) & 7))];
                    o[mt] = __builtin_amdgcn_mfma_f32_16x16x32_bf16(vf, pf.v, o[mt], 0, 0, 0);
                }
            }
        }
    }
    float inv = 1.0f / l;
#pragma unroll
    for (int mt = 0; mt < 4; mt++)
#pragma unroll
        for (int r2 = 0; r2 < 4; r2++)
            out[(size_t)(b * T + qg) * D + h * HD + mt * 16 + quad * 4 + r2] = o[mt][r2] * inv;
}

// ---------------- launch ----------------
extern "C" void kernel_launch(void* const* d_in, const int* in_sizes, int n_in,
                              void* d_out, int out_size, void* d_ws, size_t ws_size,
                              hipStream_t stream) {
    const float* x   = (const float*)d_in[0];
    const float* cs  = (const float*)d_in[1];
    const float* sn  = (const float*)d_in[2];
    const float* wq  = (const float*)d_in[3];
    const float* wk  = (const float*)d_in[4];
    const float* wv  = (const float*)d_in[5];
    const float* wo  = (const float*)d_in[6];
    const float* gq  = (const float*)d_in[7];
    const float* gk  = (const float*)d_in[8];
    const float* gv  = (const float*)d_in[9];
    const float* go  = (const float*)d_in[10];
    float* out = (float*)d_out;

    uint8_t* w = (uint8_t*)d_ws;
    double* wsum  = (double*)w;
    float* wscale = (float*)(w + 64);
    float* xs     = (float*)(w + 256);
    size_t off = 256 + 4 * (size_t)R * 4;
    int8_t* Wq8 = (int8_t*)(w + off); off += (size_t)D * D;
    int8_t* Wk8 = (int8_t*)(w + off); off += (size_t)OKV * D;
    int8_t* Wv8 = (int8_t*)(w + off); off += (size_t)OKV * D;
    int8_t* Wo8 = (int8_t*)(w + off); off += (size_t)D * D;
    int8_t* Xq_q = (int8_t*)(w + off); off += (size_t)R * D;
    int8_t* Xq_k = (int8_t*)(w + off); off += (size_t)R * D;
    int8_t* Xq_v = (int8_t*)(w + off); off += (size_t)R * D;
    float* qb = (float*)(w + off); off += (size_t)R * D * 4;
    float* kb = (float*)(w + off); off += (size_t)R * OKV * 4;
    float* vb = (float*)(w + off); off += (size_t)R * OKV * 4;
    uint16_t* qhb = (uint16_t*)(w + off); off += (size_t)R * D * 2;
    // overlays (regions dead by the time they're written):
    uint16_t* khb = (uint16_t*)Xq_v;   // 4MB into 8MB region, dead after gemm v
    uint16_t* vhb = (uint16_t*)Xq_k;   // dead after gemm k
    float*    ab  = qb;                // dead after rope q
    int8_t*   Aq8 = Xq_q;              // dead after gemm q

    hipMemsetAsync(wsum, 0, 64, stream);

    absmean_kernel<<<512, 256, 0, stream>>>(wq, D * D, wsum + 0);
    absmean_kernel<<<512, 256, 0, stream>>>(wk, OKV * D, wsum + 1);
    absmean_kernel<<<512, 256, 0, stream>>>(wv, OKV * D, wsum + 2);
    absmean_kernel<<<512, 256, 0, stream>>>(wo, D * D, wsum + 3);
    finalize_ws_kernel<<<1, 64, 0, stream>>>(wsum, wscale, D * D, OKV * D, OKV * D, D * D);

    quantw_kernel<<<4096, 256, 0, stream>>>(wq, Wq8, D * D, wscale, 0);
    quantw_kernel<<<1024, 256, 0, stream>>>(wk, Wk8, OKV * D, wscale, 1);
    quantw_kernel<<<1024, 256, 0, stream>>>(wv, Wv8, OKV * D, wscale, 2);
    quantw_kernel<<<4096, 256, 0, stream>>>(wo, Wo8, D * D, wscale, 3);

    rmsq_kernel<<<R, 256, 0, stream>>>(x, gq, Xq_q, xs + 0 * R);
    rmsq_kernel<<<R, 256, 0, stream>>>(x, gk, Xq_k, xs + 1 * R);
    rmsq_kernel<<<R, 256, 0, stream>>>(x, gv, Xq_v, xs + 2 * R);

    gemm_i8_kernel<<<dim3(D / 32, R / 32), dim3(16, 16), 0, stream>>>(Xq_q, Wq8, qb, xs + 0 * R, wscale, 0, D);
    gemm_i8_kernel<<<dim3(OKV / 32, R / 32), dim3(16, 16), 0, stream>>>(Xq_k, Wk8, kb, xs + 1 * R, wscale, 1, OKV);
    gemm_i8_kernel<<<dim3(OKV / 32, R / 32), dim3(16, 16), 0, stream>>>(Xq_v, Wv8, vb, xs + 2 * R, wscale, 2, OKV);

    {
        int totq = R * H * 32;
        rope_bf16_kernel<<<(totq + 255) / 256, 256, 0, stream>>>(qb, cs, sn, qhb, H, totq);
        int totk = R * KVH * 32;
        rope_bf16_kernel<<<(totk + 255) / 256, 256, 0, stream>>>(kb, cs, sn, khb, KVH, totk);
        int totv = R * OKV;
        cvt_bf16_kernel<<<(totv + 255) / 256, 256, 0, stream>>>(vb, vhb, totv);
    }

    attn_mfma_kernel<<<dim3(T / 64, H, B), 256, 0, stream>>>(qhb, khb, vhb, ab);

    rmsq_kernel<<<R, 256, 0, stream>>>(ab, go, Aq8, xs + 3 * R);
    gemm_i8_kernel<<<dim3(D / 32, R / 32), dim3(16, 16), 0, stream>>>(Aq8, Wo8, out, xs + 3 * R, wscale, 3, D);
}

// Round 3
// 522.511 us; speedup vs baseline: 6.2287x; 2.2345x over previous
//
#include <hip/hip_runtime.h>
#include <stdint.h>

// Problem constants (fixed by setup_inputs)
constexpr int B   = 2;
constexpr int T   = 2048;
constexpr int D   = 2048;
constexpr int H   = 32;
constexpr int KVH = 8;
constexpr int HD  = 64;          // head dim
constexpr int R   = B * T;       // 4096 rows
constexpr int OKV = KVH * HD;    // 512

using bf16x8 = __attribute__((ext_vector_type(8))) __bf16;
using f32x4  = __attribute__((ext_vector_type(4))) float;
using i32x4  = __attribute__((ext_vector_type(4))) int;

__device__ inline uint16_t f2bf(float f) {
    uint32_t u = __float_as_uint(f);
    u += 0x7fff + ((u >> 16) & 1);   // RNE
    return (uint16_t)(u >> 16);
}

// async global->LDS, 16B per lane; LDS dest = (wave-uniform) ldsbase + lane*16
__device__ inline void async16(const void* g, void* l) {
    __builtin_amdgcn_global_load_lds((const __attribute__((address_space(1))) unsigned int*)g,
                                     (__attribute__((address_space(3))) unsigned int*)l,
                                     16, 0, 0);
}

// ---------------- weight scale: mean(|w|) ----------------
__global__ void absmean_kernel(const float* __restrict__ w, int n, double* __restrict__ sum) {
    __shared__ float red[256];
    int tid = threadIdx.x;
    float s = 0.f;
    for (int i = blockIdx.x * 256 + tid; i < n; i += gridDim.x * 256)
        s += fabsf(w[i]);
    red[tid] = s;
    __syncthreads();
    for (int st = 128; st > 0; st >>= 1) {
        if (tid < st) red[tid] += red[tid + st];
        __syncthreads();
    }
    if (tid == 0) atomicAdd(sum, (double)red[0]);
}

__global__ void finalize_ws_kernel(const double* __restrict__ sums, float* __restrict__ wsc,
                                   int n0, int n1, int n2, int n3) {
    int i = threadIdx.x;
    int ns[4] = {n0, n1, n2, n3};
    if (i < 4) {
        float m = (float)(sums[i] / (double)ns[i]);
        wsc[i] = fmaxf(m, 1e-5f);
    }
}

// ---------------- ternary weight quantization ----------------
__global__ void quantw_kernel(const float* __restrict__ w, int8_t* __restrict__ w8, int n,
                              const float* __restrict__ wsc, int wi) {
    float ws = wsc[wi];
    for (int i = blockIdx.x * 256 + threadIdx.x; i < n; i += gridDim.x * 256) {
        float q = rintf(w[i] / ws);
        q = fminf(fmaxf(q, -1.f), 1.f);
        w8[i] = (int8_t)q;
    }
}

// ---------------- fused rmsnorm + absmax int8 quant for q,k,v (reads x once) -------
__global__ __launch_bounds__(256) void rmsq3_kernel(const float* __restrict__ X,
        const float* __restrict__ g0, const float* __restrict__ g1, const float* __restrict__ g2,
        int8_t* __restrict__ o0, int8_t* __restrict__ o1, int8_t* __restrict__ o2,
        float* __restrict__ s0, float* __restrict__ s1, float* __restrict__ s2) {
    __shared__ float red[256];
    int row = blockIdx.x, tid = threadIdx.x;
    const float* xr = X + (size_t)row * D;
    float xv[8];
    float ss = 0.f;
#pragma unroll
    for (int i = 0; i < 8; i++) { xv[i] = xr[tid + 256 * i]; ss += xv[i] * xv[i]; }
    red[tid] = ss;
    __syncthreads();
    for (int st = 128; st > 0; st >>= 1) {
        if (tid < st) red[tid] += red[tid + st];
        __syncthreads();
    }
    float rstd = 1.0f / sqrtf(red[0] / (float)D + 1e-6f);

    const float* gs[3] = {g0, g1, g2};
    int8_t* os[3] = {o0, o1, o2};
    float* sc[3] = {s0, s1, s2};
#pragma unroll
    for (int v = 0; v < 3; v++) {
        float xn[8];
        float amax = 0.f;
#pragma unroll
        for (int i = 0; i < 8; i++) {
            xn[i] = xv[i] * rstd * gs[v][tid + 256 * i];
            amax = fmaxf(amax, fabsf(xn[i]));
        }
        __syncthreads();
        red[tid] = amax;
        __syncthreads();
        for (int st = 128; st > 0; st >>= 1) {
            if (tid < st) red[tid] = fmaxf(red[tid], red[tid + st]);
            __syncthreads();
        }
        float xsv = fmaxf(red[0], 1e-5f);
        float q127 = 127.0f / xsv;
#pragma unroll
        for (int i = 0; i < 8; i++) {
            float q = rintf(xn[i] * q127);
            q = fminf(fmaxf(q, -128.f), 127.f);
            os[v][(size_t)row * D + tid + 256 * i] = (int8_t)q;
        }
        if (tid == 0) sc[v][row] = xsv;
    }
}

// ---------------- rmsnorm + quant (single, for o-proj input) ----------------
__global__ void rmsq_kernel(const float* __restrict__ X, const float* __restrict__ g,
                            int8_t* __restrict__ Xq, float* __restrict__ xs_out) {
    __shared__ float red[256];
    int row = blockIdx.x;
    int tid = threadIdx.x;
    const float* xr = X + (size_t)row * D;

    float ss = 0.f;
    for (int i = tid; i < D; i += 256) { float v = xr[i]; ss += v * v; }
    red[tid] = ss;
    __syncthreads();
    for (int st = 128; st > 0; st >>= 1) {
        if (tid < st) red[tid] += red[tid + st];
        __syncthreads();
    }
    float ms = red[0] / (float)D;
    float rstd = 1.0f / sqrtf(ms + 1e-6f);
    __syncthreads();

    float amax = 0.f;
    for (int i = tid; i < D; i += 256) {
        float xn = xr[i] * rstd * g[i];
        amax = fmaxf(amax, fabsf(xn));
    }
    red[tid] = amax;
    __syncthreads();
    for (int st = 128; st > 0; st >>= 1) {
        if (tid < st) red[tid] = fmaxf(red[tid], red[tid + st]);
        __syncthreads();
    }
    float xs = fmaxf(red[0], 1e-5f);

    for (int i = tid; i < D; i += 256) {
        float xn = xr[i] * rstd * g[i];
        float q = rintf(xn * 127.0f / xs);
        q = fminf(fmaxf(q, -128.f), 127.f);
        Xq[(size_t)row * D + i] = (int8_t)q;
    }
    if (tid == 0) xs_out[row] = xs;
}

// ---------------- i8 MFMA GEMM: out[r,o] = dot(Xq[r,:],W8[o,:]) * wsc*xs[r]/127 ----
// 128xBN tile, BK=128 bytes, 4 waves. LDS chunks XOR-swizzled via source address
// permutation so ds_read_b128 fragment reads are bank-conflict-free while the
// global_load_lds dest stays contiguous (wave-uniform base + lane*16).
template<int BN>
__global__ __launch_bounds__(256) void gemm_i8_mfma(const int8_t* __restrict__ Xq,
                                                    const int8_t* __restrict__ W8,
                                                    float* __restrict__ out,
                                                    const float* __restrict__ xs,
                                                    const float* __restrict__ wsc, int wi,
                                                    int O) {
    constexpr int NT = BN / 32;          // n-tiles per wave
    __shared__ __align__(16) uint8_t As[128 * 128];
    __shared__ __align__(16) uint8_t Bs[BN * 128];

    const int tid  = threadIdx.x;
    const int lane = tid & 63;
    const int wv   = tid >> 6;
    const int n    = lane & 15, quad = lane >> 4;
    const int row0 = blockIdx.y * 128;
    const int col0 = blockIdx.x * BN;
    const int ws_m = (wv >> 1) * 64;
    const int ws_n = (wv & 1) * (BN / 2);

    i32x4 acc[4][NT] = {};

    for (int k0 = 0; k0 < D; k0 += 128) {
        __syncthreads();
        // stage A tile: 1024 16B-chunks, 4 calls/wave
#pragma unroll
        for (int j = 0; j < 4; j++) {
            int p = wv * 256 + j * 64 + lane;       // linear LDS position
            int r = p >> 3, s = p & 7;
            int c = s ^ (r & 7);                    // source chunk (inverse swizzle)
            async16(Xq + (size_t)(row0 + r) * D + k0 + c * 16,
                    &As[(size_t)(wv * 256 + j * 64) * 16]);
        }
        // stage B tile: BN*8 chunks, NT calls/wave
#pragma unroll
        for (int j = 0; j < NT; j++) {
            int p = wv * (BN * 2) + j * 64 + lane;
            int r = p >> 3, s = p & 7;
            int c = s ^ (r & 7);
            async16(W8 + (size_t)(col0 + r) * D + k0 + c * 16,
                    &Bs[(size_t)(wv * (BN * 2) + j * 64) * 16]);
        }
        __syncthreads();
#pragma unroll
        for (int t = 0; t < 2; t++) {
            i32x4 af[4], bfr[NT];
#pragma unroll
            for (int mt = 0; mt < 4; mt++) {
                int r = ws_m + mt * 16 + n;
                af[mt] = *(const i32x4*)&As[r * 128 + (((t * 4 + quad) ^ (r & 7)) * 16)];
            }
#pragma unroll
            for (int nt = 0; nt < NT; nt++) {
                int r = ws_n + nt * 16 + n;
                bfr[nt] = *(const i32x4*)&Bs[r * 128 + (((t * 4 + quad) ^ (r & 7)) * 16)];
            }
#pragma unroll
            for (int mt = 0; mt < 4; mt++)
#pragma unroll
                for (int nt = 0; nt < NT; nt++)
                    acc[mt][nt] = __builtin_amdgcn_mfma_i32_16x16x64_i8(af[mt], bfr[nt], acc[mt][nt], 0, 0, 0);
        }
    }
    // epilogue: C/D layout col=lane&15, row=quad*4+reg
    float w = wsc[wi];
#pragma unroll
    for (int mt = 0; mt < 4; mt++) {
#pragma unroll
        for (int r2 = 0; r2 < 4; r2++) {
            int row = row0 + ws_m + mt * 16 + quad * 4 + r2;
            float f = w * xs[row] * (1.0f / 127.0f);
#pragma unroll
            for (int nt = 0; nt < NT; nt++) {
                int col = col0 + ws_n + nt * 16 + n;
                out[(size_t)row * O + col] = (float)acc[mt][nt][r2] * f;
            }
        }
    }
}

// ---------------- RoPE fp32 -> bf16 ----------------
__global__ void rope_bf16_kernel(const float* __restrict__ x, const float* __restrict__ cs,
                                 const float* __restrict__ sn, uint16_t* __restrict__ o,
                                 int NH, int total) {
    int idx = blockIdx.x * 256 + threadIdx.x;
    if (idx >= total) return;
    int i = idx & 31;                 // 0..31
    int hh = (idx >> 5) % NH;
    int bt = idx / (32 * NH);         // b*T + t
    int t = bt % T;
    size_t base = ((size_t)bt * NH + hh) * HD;
    float x0 = x[base + i], x1 = x[base + i + 32];
    float c0 = cs[t * HD + i], c1 = cs[t * HD + i + 32];
    float s0 = sn[t * HD + i], s1 = sn[t * HD + i + 32];
    o[base + i]      = f2bf(x0 * c0 - x1 * s0);
    o[base + i + 32] = f2bf(x1 * c1 + x0 * s1);
}

__global__ void cvt_bf16_kernel(const float* __restrict__ x, uint16_t* __restrict__ o, int ntot) {
    int i = blockIdx.x * 256 + threadIdx.x;
    if (i < ntot) o[i] = f2bf(x[i]);
}

// ---------------- MFMA flash attention (S^T = K Q^T, O^T = V^T P^T) ----------------
__global__ __launch_bounds__(256) void attn_mfma_kernel(const uint16_t* __restrict__ qh,
                                                        const uint16_t* __restrict__ kh,
                                                        const uint16_t* __restrict__ vh,
                                                        float* __restrict__ out) {
    __shared__ uint16_t Ks[64 * 72];      // [key][d], stride 72
    __shared__ uint16_t Vt[64 * 72];      // [d][key^swizzle], stride 72
    __shared__ uint16_t Pt[4][64 * 18];   // per-wave P^T [key][q], stride 18

    const int tid  = threadIdx.x;
    const int lane = tid & 63;
    const int wv   = tid >> 6;
    const int bx = blockIdx.x, h = blockIdx.y, b = blockIdx.z;
    const int q0 = bx * 64;
    const int kvh = h >> 2;               // n_rep = 4
    const int n = lane & 15, quad = lane >> 4;
    const int qg = q0 + wv * 16 + n;      // this lane's q column (global row idx)

    bf16x8 qf[2];
    {
        const uint16_t* qp = qh + (size_t)(b * T + qg) * D + h * HD + quad * 8;
        qf[0] = *(const bf16x8*)(qp);
        qf[1] = *(const bf16x8*)(qp + 32);
    }

    f32x4 o[4] = {{0.f,0.f,0.f,0.f},{0.f,0.f,0.f,0.f},{0.f,0.f,0.f,0.f},{0.f,0.f,0.f,0.f}};
    float m = -INFINITY, l = 0.f;

    const int nchunks = bx + 1;
    const int sr = tid >> 2;            // staging key row 0..63
    const int sc = (tid & 3) * 16;      // staging col base

    for (int ch = 0; ch < nchunks; ch++) {
        const int t0 = ch * 64;
        __syncthreads();
        {
            const uint16_t* ksrc = kh + (size_t)(b * T + t0 + sr) * OKV + kvh * HD + sc;
            *(uint4*)&Ks[sr * 72 + sc]     = *(const uint4*)(ksrc);
            *(uint4*)&Ks[sr * 72 + sc + 8] = *(const uint4*)(ksrc + 8);
            const uint16_t* vsrc = vh + (size_t)(b * T + t0 + sr) * OKV + kvh * HD + sc;
#pragma unroll
            for (int half = 0; half < 2; half++) {
                int d0 = sc + half * 8;
                uint4 raw = *(const uint4*)(vsrc + half * 8);
                const uint16_t* pr = (const uint16_t*)&raw;
                int kpos = (sr & 7) + 8 * ((sr >> 3) ^ (d0 >> 3));
#pragma unroll
                for (int j = 0; j < 8; j++)
                    Vt[(d0 + j) * 72 + kpos] = pr[j];
            }
        }
        __syncthreads();

        if (t0 <= q0 + wv * 16 + 15) {
            f32x4 s[4] = {{0.f,0.f,0.f,0.f},{0.f,0.f,0.f,0.f},{0.f,0.f,0.f,0.f},{0.f,0.f,0.f,0.f}};
#pragma unroll
            for (int ks = 0; ks < 2; ks++) {
#pragma unroll
                for (int mt = 0; mt < 4; mt++) {
                    bf16x8 kf = *(const bf16x8*)&Ks[(mt * 16 + n) * 72 + ks * 32 + quad * 8];
                    s[mt] = __builtin_amdgcn_mfma_f32_16x16x32_bf16(kf, qf[ks], s[mt], 0, 0, 0);
                }
            }
            float mloc = -INFINITY;
#pragma unroll
            for (int mt = 0; mt < 4; mt++) {
#pragma unroll
                for (int r2 = 0; r2 < 4; r2++) {
                    int kg = t0 + mt * 16 + quad * 4 + r2;
                    float sv = s[mt][r2] * 0.125f;
                    sv = (kg > qg) ? -INFINITY : sv;
                    s[mt][r2] = sv;
                    mloc = fmaxf(mloc, sv);
                }
            }
            mloc = fmaxf(mloc, __shfl_xor(mloc, 16));
            mloc = fmaxf(mloc, __shfl_xor(mloc, 32));
            float mnew = fmaxf(m, mloc);
            float corr = __expf(m - mnew);
            float ls = 0.f;
#pragma unroll
            for (int mt = 0; mt < 4; mt++) {
#pragma unroll
                for (int r2 = 0; r2 < 4; r2++) {
                    float p = __expf(s[mt][r2] - mnew);
                    ls += p;
                    Pt[wv][(mt * 16 + quad * 4 + r2) * 18 + n] = f2bf(p);
                }
            }
            ls += __shfl_xor(ls, 16);
            ls += __shfl_xor(ls, 32);
            l = l * corr + ls;
            m = mnew;
#pragma unroll
            for (int mt = 0; mt < 4; mt++)
#pragma unroll
                for (int r2 = 0; r2 < 4; r2++) o[mt][r2] *= corr;

#pragma unroll
            for (int ks = 0; ks < 2; ks++) {
                union { bf16x8 v; uint16_t u[8]; } pf;
#pragma unroll
                for (int j = 0; j < 8; j++)
                    pf.u[j] = Pt[wv][(ks * 32 + quad * 8 + j) * 18 + n];
#pragma unroll
                for (int mt = 0; mt < 4; mt++) {
                    int d = mt * 16 + n;
                    bf16x8 vf = *(const bf16x8*)&Vt[d * 72 + 8 * ((ks * 4 + quad) ^ ((d >> 3) & 7))];
                    o[mt] = __builtin_amdgcn_mfma_f32_16x16x32_bf16(vf, pf.v, o[mt], 0, 0, 0);
                }
            }
        }
    }
    float inv = 1.0f / l;
#pragma unroll
    for (int mt = 0; mt < 4; mt++)
#pragma unroll
        for (int r2 = 0; r2 < 4; r2++)
            out[(size_t)(b * T + qg) * D + h * HD + mt * 16 + quad * 4 + r2] = o[mt][r2] * inv;
}

// ---------------- launch ----------------
extern "C" void kernel_launch(void* const* d_in, const int* in_sizes, int n_in,
                              void* d_out, int out_size, void* d_ws, size_t ws_size,
                              hipStream_t stream) {
    const float* x   = (const float*)d_in[0];
    const float* cs  = (const float*)d_in[1];
    const float* sn  = (const float*)d_in[2];
    const float* wq  = (const float*)d_in[3];
    const float* wk  = (const float*)d_in[4];
    const float* wv  = (const float*)d_in[5];
    const float* wo  = (const float*)d_in[6];
    const float* gq  = (const float*)d_in[7];
    const float* gk  = (const float*)d_in[8];
    const float* gv  = (const float*)d_in[9];
    const float* go  = (const float*)d_in[10];
    float* out = (float*)d_out;

    uint8_t* w = (uint8_t*)d_ws;
    double* wsum  = (double*)w;
    float* wscale = (float*)(w + 64);
    float* xs     = (float*)(w + 256);
    size_t off = 256 + 4 * (size_t)R * 4;
    int8_t* Wq8 = (int8_t*)(w + off); off += (size_t)D * D;
    int8_t* Wk8 = (int8_t*)(w + off); off += (size_t)OKV * D;
    int8_t* Wv8 = (int8_t*)(w + off); off += (size_t)OKV * D;
    int8_t* Wo8 = (int8_t*)(w + off); off += (size_t)D * D;
    int8_t* Xq_q = (int8_t*)(w + off); off += (size_t)R * D;
    int8_t* Xq_k = (int8_t*)(w + off); off += (size_t)R * D;
    int8_t* Xq_v = (int8_t*)(w + off); off += (size_t)R * D;
    float* qb = (float*)(w + off); off += (size_t)R * D * 4;
    float* kb = (float*)(w + off); off += (size_t)R * OKV * 4;
    float* vb = (float*)(w + off); off += (size_t)R * OKV * 4;
    uint16_t* qhb = (uint16_t*)(w + off); off += (size_t)R * D * 2;
    // overlays (regions dead by the time they're written):
    uint16_t* khb = (uint16_t*)Xq_v;   // dead after v gemm
    uint16_t* vhb = (uint16_t*)Xq_k;   // dead after k gemm
    float*    ab  = qb;                // dead after rope q
    int8_t*   Aq8 = Xq_q;              // dead after q gemm

    hipMemsetAsync(wsum, 0, 64, stream);

    absmean_kernel<<<512, 256, 0, stream>>>(wq, D * D, wsum + 0);
    absmean_kernel<<<512, 256, 0, stream>>>(wk, OKV * D, wsum + 1);
    absmean_kernel<<<512, 256, 0, stream>>>(wv, OKV * D, wsum + 2);
    absmean_kernel<<<512, 256, 0, stream>>>(wo, D * D, wsum + 3);
    finalize_ws_kernel<<<1, 64, 0, stream>>>(wsum, wscale, D * D, OKV * D, OKV * D, D * D);

    quantw_kernel<<<4096, 256, 0, stream>>>(wq, Wq8, D * D, wscale, 0);
    quantw_kernel<<<1024, 256, 0, stream>>>(wk, Wk8, OKV * D, wscale, 1);
    quantw_kernel<<<1024, 256, 0, stream>>>(wv, Wv8, OKV * D, wscale, 2);
    quantw_kernel<<<4096, 256, 0, stream>>>(wo, Wo8, D * D, wscale, 3);

    rmsq3_kernel<<<R, 256, 0, stream>>>(x, gq, gk, gv, Xq_q, Xq_k, Xq_v,
                                        xs + 0 * R, xs + 1 * R, xs + 2 * R);

    gemm_i8_mfma<128><<<dim3(D / 128, R / 128), 256, 0, stream>>>(Xq_q, Wq8, qb, xs + 0 * R, wscale, 0, D);
    gemm_i8_mfma<64><<<dim3(OKV / 64, R / 128), 256, 0, stream>>>(Xq_k, Wk8, kb, xs + 1 * R, wscale, 1, OKV);
    gemm_i8_mfma<64><<<dim3(OKV / 64, R / 128), 256, 0, stream>>>(Xq_v, Wv8, vb, xs + 2 * R, wscale, 2, OKV);

    {
        int totq = R * H * 32;
        rope_bf16_kernel<<<(totq + 255) / 256, 256, 0, stream>>>(qb, cs, sn, qhb, H, totq);
        int totk = R * KVH * 32;
        rope_bf16_kernel<<<(totk + 255) / 256, 256, 0, stream>>>(kb, cs, sn, khb, KVH, totk);
        int totv = R * OKV;
        cvt_bf16_kernel<<<(totv + 255) / 256, 256, 0, stream>>>(vb, vhb, totv);
    }

    attn_mfma_kernel<<<dim3(T / 64, H, B), 256, 0, stream>>>(qhb, khb, vhb, ab);

    rmsq_kernel<<<R, 256, 0, stream>>>(ab, go, Aq8, xs + 3 * R);
    gemm_i8_mfma<128><<<dim3(D / 128, R / 128), 256, 0, stream>>>(Aq8, Wo8, out, xs + 3 * R, wscale, 3, D);
}

// Round 4
// 511.527 us; speedup vs baseline: 6.3625x; 1.0215x over previous
//
#include <hip/hip_runtime.h>
#include <stdint.h>

// Problem constants (fixed by setup_inputs)
constexpr int B   = 2;
constexpr int T   = 2048;
constexpr int D   = 2048;
constexpr int H   = 32;
constexpr int KVH = 8;
constexpr int HD  = 64;          // head dim
constexpr int R   = B * T;       // 4096 rows
constexpr int OKV = KVH * HD;    // 512

using bf16x8 = __attribute__((ext_vector_type(8))) __bf16;
using f32x4  = __attribute__((ext_vector_type(4))) float;
using i32x4  = __attribute__((ext_vector_type(4))) int;

__device__ inline uint16_t f2bf(float f) {
    uint32_t u = __float_as_uint(f);
    u += 0x7fff + ((u >> 16) & 1);   // RNE
    return (uint16_t)(u >> 16);
}

// async global->LDS, 16B per lane; LDS dest = (wave-uniform) base + lane*16
__device__ inline void async16(const void* g, void* l) {
    __builtin_amdgcn_global_load_lds((const __attribute__((address_space(1))) unsigned int*)g,
                                     (__attribute__((address_space(3))) unsigned int*)l,
                                     16, 0, 0);
}

// ---------------- weight scale: mean(|w|) ----------------
__global__ void absmean_kernel(const float* __restrict__ w, int n, double* __restrict__ sum) {
    __shared__ float red[256];
    int tid = threadIdx.x;
    float s = 0.f;
    for (int i = blockIdx.x * 256 + tid; i < n; i += gridDim.x * 256)
        s += fabsf(w[i]);
    red[tid] = s;
    __syncthreads();
    for (int st = 128; st > 0; st >>= 1) {
        if (tid < st) red[tid] += red[tid + st];
        __syncthreads();
    }
    if (tid == 0) atomicAdd(sum, (double)red[0]);
}

__global__ void finalize_ws_kernel(const double* __restrict__ sums, float* __restrict__ wsc,
                                   int n0, int n1, int n2, int n3) {
    int i = threadIdx.x;
    int ns[4] = {n0, n1, n2, n3};
    if (i < 4) {
        float m = (float)(sums[i] / (double)ns[i]);
        wsc[i] = fmaxf(m, 1e-5f);
    }
}

// ---------------- ternary weight quantization ----------------
__global__ void quantw_kernel(const float* __restrict__ w, int8_t* __restrict__ w8, int n,
                              const float* __restrict__ wsc, int wi) {
    float ws = wsc[wi];
    for (int i = blockIdx.x * 256 + threadIdx.x; i < n; i += gridDim.x * 256) {
        float q = rintf(w[i] / ws);
        q = fminf(fmaxf(q, -1.f), 1.f);
        w8[i] = (int8_t)q;
    }
}

// ---------------- fused rmsnorm + absmax int8 quant for q,k,v ----------------
__global__ __launch_bounds__(256) void rmsq3_kernel(const float* __restrict__ X,
        const float* __restrict__ g0, const float* __restrict__ g1, const float* __restrict__ g2,
        int8_t* __restrict__ o0, int8_t* __restrict__ o1, int8_t* __restrict__ o2,
        float* __restrict__ s0, float* __restrict__ s1, float* __restrict__ s2) {
    __shared__ float red[256];
    int row = blockIdx.x, tid = threadIdx.x;
    const float* xr = X + (size_t)row * D;
    float xv[8];
    float ss = 0.f;
#pragma unroll
    for (int i = 0; i < 8; i++) { xv[i] = xr[tid + 256 * i]; ss += xv[i] * xv[i]; }
    red[tid] = ss;
    __syncthreads();
    for (int st = 128; st > 0; st >>= 1) {
        if (tid < st) red[tid] += red[tid + st];
        __syncthreads();
    }
    float rstd = 1.0f / sqrtf(red[0] / (float)D + 1e-6f);

    const float* gs[3] = {g0, g1, g2};
    int8_t* os[3] = {o0, o1, o2};
    float* sc[3] = {s0, s1, s2};
#pragma unroll
    for (int v = 0; v < 3; v++) {
        float xn[8];
        float amax = 0.f;
#pragma unroll
        for (int i = 0; i < 8; i++) {
            xn[i] = xv[i] * rstd * gs[v][tid + 256 * i];
            amax = fmaxf(amax, fabsf(xn[i]));
        }
        __syncthreads();
        red[tid] = amax;
        __syncthreads();
        for (int st = 128; st > 0; st >>= 1) {
            if (tid < st) red[tid] = fmaxf(red[tid], red[tid + st]);
            __syncthreads();
        }
        float xsv = fmaxf(red[0], 1e-5f);
        float q127 = 127.0f / xsv;
#pragma unroll
        for (int i = 0; i < 8; i++) {
            float q = rintf(xn[i] * q127);
            q = fminf(fmaxf(q, -128.f), 127.f);
            os[v][(size_t)row * D + tid + 256 * i] = (int8_t)q;
        }
        if (tid == 0) sc[v][row] = xsv;
    }
}

// ---------------- rmsnorm + quant (single, for o-proj input) ----------------
__global__ void rmsq_kernel(const float* __restrict__ X, const float* __restrict__ g,
                            int8_t* __restrict__ Xq, float* __restrict__ xs_out) {
    __shared__ float red[256];
    int row = blockIdx.x;
    int tid = threadIdx.x;
    const float* xr = X + (size_t)row * D;

    float ss = 0.f;
    for (int i = tid; i < D; i += 256) { float v = xr[i]; ss += v * v; }
    red[tid] = ss;
    __syncthreads();
    for (int st = 128; st > 0; st >>= 1) {
        if (tid < st) red[tid] += red[tid + st];
        __syncthreads();
    }
    float ms = red[0] / (float)D;
    float rstd = 1.0f / sqrtf(ms + 1e-6f);
    __syncthreads();

    float amax = 0.f;
    for (int i = tid; i < D; i += 256) {
        float xn = xr[i] * rstd * g[i];
        amax = fmaxf(amax, fabsf(xn));
    }
    red[tid] = amax;
    __syncthreads();
    for (int st = 128; st > 0; st >>= 1) {
        if (tid < st) red[tid] = fmaxf(red[tid], red[tid + st]);
        __syncthreads();
    }
    float xs = fmaxf(red[0], 1e-5f);

    for (int i = tid; i < D; i += 256) {
        float xn = xr[i] * rstd * g[i];
        float q = rintf(xn * 127.0f / xs);
        q = fminf(fmaxf(q, -128.f), 127.f);
        Xq[(size_t)row * D + i] = (int8_t)q;
    }
    if (tid == 0) xs_out[row] = xs;
}

// ---------------- i8 MFMA GEMM ----------------
template<int BN>
__global__ __launch_bounds__(256) void gemm_i8_mfma(const int8_t* __restrict__ Xq,
                                                    const int8_t* __restrict__ W8,
                                                    float* __restrict__ out,
                                                    const float* __restrict__ xs,
                                                    const float* __restrict__ wsc, int wi,
                                                    int O) {
    constexpr int NT = BN / 32;          // n-tiles per wave
    __shared__ __align__(16) uint8_t As[128 * 128];
    __shared__ __align__(16) uint8_t Bs[BN * 128];

    const int tid  = threadIdx.x;
    const int lane = tid & 63;
    const int wv   = tid >> 6;
    const int n    = lane & 15, quad = lane >> 4;
    const int row0 = blockIdx.y * 128;
    const int col0 = blockIdx.x * BN;
    const int ws_m = (wv >> 1) * 64;
    const int ws_n = (wv & 1) * (BN / 2);

    i32x4 acc[4][NT] = {};

    for (int k0 = 0; k0 < D; k0 += 128) {
        __syncthreads();
#pragma unroll
        for (int j = 0; j < 4; j++) {
            int p = wv * 256 + j * 64 + lane;
            int r = p >> 3, s = p & 7;
            int c = s ^ (r & 7);
            async16(Xq + (size_t)(row0 + r) * D + k0 + c * 16,
                    &As[(size_t)(wv * 256 + j * 64) * 16]);
        }
#pragma unroll
        for (int j = 0; j < NT; j++) {
            int p = wv * (BN * 2) + j * 64 + lane;
            int r = p >> 3, s = p & 7;
            int c = s ^ (r & 7);
            async16(W8 + (size_t)(col0 + r) * D + k0 + c * 16,
                    &Bs[(size_t)(wv * (BN * 2) + j * 64) * 16]);
        }
        __syncthreads();
#pragma unroll
        for (int t = 0; t < 2; t++) {
            i32x4 af[4], bfr[NT];
#pragma unroll
            for (int mt = 0; mt < 4; mt++) {
                int r = ws_m + mt * 16 + n;
                af[mt] = *(const i32x4*)&As[r * 128 + (((t * 4 + quad) ^ (r & 7)) * 16)];
            }
#pragma unroll
            for (int nt = 0; nt < NT; nt++) {
                int r = ws_n + nt * 16 + n;
                bfr[nt] = *(const i32x4*)&Bs[r * 128 + (((t * 4 + quad) ^ (r & 7)) * 16)];
            }
#pragma unroll
            for (int mt = 0; mt < 4; mt++)
#pragma unroll
                for (int nt = 0; nt < NT; nt++)
                    acc[mt][nt] = __builtin_amdgcn_mfma_i32_16x16x64_i8(af[mt], bfr[nt], acc[mt][nt], 0, 0, 0);
        }
    }
    float w = wsc[wi];
#pragma unroll
    for (int mt = 0; mt < 4; mt++) {
#pragma unroll
        for (int r2 = 0; r2 < 4; r2++) {
            int row = row0 + ws_m + mt * 16 + quad * 4 + r2;
            float f = w * xs[row] * (1.0f / 127.0f);
#pragma unroll
            for (int nt = 0; nt < NT; nt++) {
                int col = col0 + ws_n + nt * 16 + n;
                out[(size_t)row * O + col] = (float)acc[mt][nt][r2] * f;
            }
        }
    }
}

// ---------------- RoPE fp32 -> bf16 ----------------
__global__ void rope_bf16_kernel(const float* __restrict__ x, const float* __restrict__ cs,
                                 const float* __restrict__ sn, uint16_t* __restrict__ o,
                                 int NH, int total) {
    int idx = blockIdx.x * 256 + threadIdx.x;
    if (idx >= total) return;
    int i = idx & 31;                 // 0..31
    int hh = (idx >> 5) % NH;
    int bt = idx / (32 * NH);         // b*T + t
    int t = bt % T;
    size_t base = ((size_t)bt * NH + hh) * HD;
    float x0 = x[base + i], x1 = x[base + i + 32];
    float c0 = cs[t * HD + i], c1 = cs[t * HD + i + 32];
    float s0 = sn[t * HD + i], s1 = sn[t * HD + i + 32];
    o[base + i]      = f2bf(x0 * c0 - x1 * s0);
    o[base + i + 32] = f2bf(x1 * c1 + x0 * s1);
}

// ---------------- V transpose: [t][kvh*64+d] f32 -> [b*KVH+kvh][d][t] bf16 --------
__global__ __launch_bounds__(256) void vtrans_kernel(const float* __restrict__ vb,
                                                     uint16_t* __restrict__ vt) {
    __shared__ float tile[64][65];
    int t0 = blockIdx.x * 64;
    int hb = blockIdx.y;              // b*KVH + kvh
    int b = hb >> 3, kvh = hb & 7;
    int tid = threadIdx.x;
    int r = tid >> 2, cg = (tid & 3) * 16;
#pragma unroll
    for (int j = 0; j < 4; j++) {
        float4 v4 = *(const float4*)(vb + (size_t)(b * T + t0 + r) * OKV + kvh * HD + cg + j * 4);
        tile[r][cg + j * 4 + 0] = v4.x;
        tile[r][cg + j * 4 + 1] = v4.y;
        tile[r][cg + j * 4 + 2] = v4.z;
        tile[r][cg + j * 4 + 3] = v4.w;
    }
    __syncthreads();
    int d = tid >> 2, tg = (tid & 3) * 16;
    uint16_t pk[16];
#pragma unroll
    for (int j = 0; j < 16; j++) pk[j] = f2bf(tile[tg + j][d]);
    *(uint4*)(vt + ((size_t)hb * 64 + d) * T + t0 + tg)     = *(uint4*)&pk[0];
    *(uint4*)(vt + ((size_t)hb * 64 + d) * T + t0 + tg + 8) = *(uint4*)&pk[8];
}

// ---------------- MFMA flash attention, 128 q per block ----------------
// S^T = K Q^T, O^T = V^T P^T. grid (T/128, H, B), 4 waves; wave handles q-tiles
// wv*32+{0,16}. K [key][d] and V^T [d][key] staged via swizzled global_load_lds.
__global__ __launch_bounds__(256) void attn_mfma_kernel(const uint16_t* __restrict__ qh,
                                                        const uint16_t* __restrict__ kh,
                                                        const uint16_t* __restrict__ vt,
                                                        float* __restrict__ out) {
    __shared__ __align__(16) uint16_t Ks[64 * 64];     // [key][d] chunk-swizzled
    __shared__ __align__(16) uint16_t Vt[64 * 64];     // [d][key] chunk-swizzled
    __shared__ __align__(16) uint16_t Pw[4][32 * 72];  // per-wave P [q][key], pad 72

    const int tid  = threadIdx.x;
    const int lane = tid & 63;
    const int wv   = tid >> 6;
    const int bx = (int)gridDim.x - 1 - (int)blockIdx.x;   // big blocks first
    const int h = blockIdx.y, b = blockIdx.z;
    const int q0 = bx * 128;
    const int kvh = h >> 2;               // n_rep = 4
    const int n = lane & 15, quad = lane >> 4;

    // Q B-frags for both tiles: lane holds d = ks*32 + quad*8 + j, col q = n
    bf16x8 qf[2][2];
#pragma unroll
    for (int tl = 0; tl < 2; tl++) {
        const uint16_t* qp = qh + (size_t)(b * T + q0 + wv * 32 + tl * 16 + n) * D + h * HD + quad * 8;
        qf[tl][0] = *(const bf16x8*)(qp);
        qf[tl][1] = *(const bf16x8*)(qp + 32);
    }

    f32x4 o[2][4] = {};
    float m[2] = {-INFINITY, -INFINITY}, l[2] = {0.f, 0.f};

    const int nchunks = bx * 2 + 2;
    const uint16_t* krow_base = kh + (size_t)b * T * OKV + kvh * HD;
    const uint16_t* vrow_base = vt + ((size_t)(b * KVH + kvh) * 64) * T;

    for (int ch = 0; ch < nchunks; ch++) {
        const int t0 = ch * 64;
        __syncthreads();
        // stage K and V^T chunks: 512 16B-chunks each, XOR-swizzled source cols
#pragma unroll
        for (int j = 0; j < 2; j++) {
            int p = wv * 128 + j * 64 + lane;
            int r = p >> 3, s = p & 7;
            int c = s ^ (r & 7);
            async16(krow_base + (size_t)(t0 + r) * OKV + c * 8, &Ks[(wv * 128 + j * 64) * 8]);
            async16(vrow_base + (size_t)r * T + t0 + c * 8,     &Vt[(wv * 128 + j * 64) * 8]);
        }
        __syncthreads();

        if (t0 > q0 + wv * 32 + 31) continue;   // whole wave done (can't happen mid-loop but safe)

        // K A-frags (shared across both q-tiles)
        bf16x8 kf[2][4];
#pragma unroll
        for (int ks = 0; ks < 2; ks++)
#pragma unroll
            for (int mt = 0; mt < 4; mt++) {
                int r = mt * 16 + n;
                kf[ks][mt] = *(const bf16x8*)&Ks[r * 64 + (((ks * 4 + quad) ^ (n & 7)) * 8)];
            }

#pragma unroll
        for (int tl = 0; tl < 2; tl++) {
            int q_lo = q0 + wv * 32 + tl * 16;
            if (t0 > q_lo + 15) continue;
            int qg = q_lo + n;
            f32x4 s[4] = {};
#pragma unroll
            for (int ks = 0; ks < 2; ks++)
#pragma unroll
                for (int mt = 0; mt < 4; mt++)
                    s[mt] = __builtin_amdgcn_mfma_f32_16x16x32_bf16(kf[ks][mt], qf[tl][ks], s[mt], 0, 0, 0);

            bool diag = (t0 + 63 > q_lo);
            float mloc = -INFINITY;
#pragma unroll
            for (int mt = 0; mt < 4; mt++) {
#pragma unroll
                for (int r2 = 0; r2 < 4; r2++) {
                    float sv = s[mt][r2] * 0.125f;
                    if (diag) {
                        int kg = t0 + mt * 16 + quad * 4 + r2;
                        sv = (kg > qg) ? -INFINITY : sv;
                    }
                    s[mt][r2] = sv;
                    mloc = fmaxf(mloc, sv);
                }
            }
            mloc = fmaxf(mloc, __shfl_xor(mloc, 16));
            mloc = fmaxf(mloc, __shfl_xor(mloc, 32));
            float mnew = fmaxf(m[tl], mloc);
            float corr = __expf(m[tl] - mnew);
            float ls = 0.f;
#pragma unroll
            for (int mt = 0; mt < 4; mt++) {
                uint32_t pk[2];
#pragma unroll
                for (int r2 = 0; r2 < 4; r2++) {
                    float p = __expf(s[mt][r2] - mnew);
                    ls += p;
                    ((uint16_t*)pk)[r2] = f2bf(p);
                }
                *(uint2*)&Pw[wv][(tl * 16 + n) * 72 + mt * 16 + quad * 4] = *(uint2*)pk;
            }
            ls += __shfl_xor(ls, 16);
            ls += __shfl_xor(ls, 32);
            l[tl] = l[tl] * corr + ls;
            m[tl] = mnew;
#pragma unroll
            for (int mt = 0; mt < 4; mt++)
#pragma unroll
                for (int r2 = 0; r2 < 4; r2++) o[tl][mt][r2] *= corr;
        }

        // V^T A-frags (shared across tiles)
        bf16x8 vf[2][4];
#pragma unroll
        for (int ks = 0; ks < 2; ks++)
#pragma unroll
            for (int mt = 0; mt < 4; mt++) {
                int r = mt * 16 + n;
                vf[ks][mt] = *(const bf16x8*)&Vt[r * 64 + (((ks * 4 + quad) ^ (n & 7)) * 8)];
            }
#pragma unroll
        for (int tl = 0; tl < 2; tl++) {
            int q_lo = q0 + wv * 32 + tl * 16;
            if (t0 > q_lo + 15) continue;
#pragma unroll
            for (int ks = 0; ks < 2; ks++) {
                bf16x8 pf = *(const bf16x8*)&Pw[wv][(tl * 16 + n) * 72 + ks * 32 + quad * 8];
#pragma unroll
                for (int mt = 0; mt < 4; mt++)
                    o[tl][mt] = __builtin_amdgcn_mfma_f32_16x16x32_bf16(vf[ks][mt], pf, o[tl][mt], 0, 0, 0);
            }
        }
    }

#pragma unroll
    for (int tl = 0; tl < 2; tl++) {
        int qg = q0 + wv * 32 + tl * 16 + n;
        float inv = 1.0f / l[tl];
#pragma unroll
        for (int mt = 0; mt < 4; mt++) {
            f32x4 ov;
#pragma unroll
            for (int r2 = 0; r2 < 4; r2++) ov[r2] = o[tl][mt][r2] * inv;
            *(f32x4*)(out + (size_t)(b * T + qg) * D + h * HD + mt * 16 + quad * 4) = ov;
        }
    }
}

// ---------------- launch ----------------
extern "C" void kernel_launch(void* const* d_in, const int* in_sizes, int n_in,
                              void* d_out, int out_size, void* d_ws, size_t ws_size,
                              hipStream_t stream) {
    const float* x   = (const float*)d_in[0];
    const float* cs  = (const float*)d_in[1];
    const float* sn  = (const float*)d_in[2];
    const float* wq  = (const float*)d_in[3];
    const float* wk  = (const float*)d_in[4];
    const float* wv  = (const float*)d_in[5];
    const float* wvv = (const float*)d_in[5];
    const float* wo  = (const float*)d_in[6];
    const float* gq  = (const float*)d_in[7];
    const float* gk  = (const float*)d_in[8];
    const float* gv  = (const float*)d_in[9];
    const float* go  = (const float*)d_in[10];
    float* out = (float*)d_out;
    (void)wvv;

    uint8_t* w = (uint8_t*)d_ws;
    double* wsum  = (double*)w;
    float* wscale = (float*)(w + 64);
    float* xs     = (float*)(w + 256);
    size_t off = 256 + 4 * (size_t)R * 4;
    int8_t* Wq8 = (int8_t*)(w + off); off += (size_t)D * D;
    int8_t* Wk8 = (int8_t*)(w + off); off += (size_t)OKV * D;
    int8_t* Wv8 = (int8_t*)(w + off); off += (size_t)OKV * D;
    int8_t* Wo8 = (int8_t*)(w + off); off += (size_t)D * D;
    int8_t* Xq_q = (int8_t*)(w + off); off += (size_t)R * D;
    int8_t* Xq_k = (int8_t*)(w + off); off += (size_t)R * D;
    int8_t* Xq_v = (int8_t*)(w + off); off += (size_t)R * D;
    float* qb = (float*)(w + off); off += (size_t)R * D * 4;
    float* kb = (float*)(w + off); off += (size_t)R * OKV * 4;
    float* vb = (float*)(w + off); off += (size_t)R * OKV * 4;
    uint16_t* qhb = (uint16_t*)(w + off); off += (size_t)R * D * 2;
    // overlays (regions dead by the time they're written):
    uint16_t* khb = (uint16_t*)Xq_v;   // dead after v gemm
    uint16_t* vtb = (uint16_t*)Xq_k;   // dead after k gemm; 4MB needed, 8MB region
    float*    ab  = qb;                // dead after rope q
    int8_t*   Aq8 = Xq_q;              // dead after q gemm (rewritten after attention)

    hipMemsetAsync(wsum, 0, 64, stream);

    absmean_kernel<<<512, 256, 0, stream>>>(wq, D * D, wsum + 0);
    absmean_kernel<<<512, 256, 0, stream>>>(wk, OKV * D, wsum + 1);
    absmean_kernel<<<512, 256, 0, stream>>>(wv, OKV * D, wsum + 2);
    absmean_kernel<<<512, 256, 0, stream>>>(wo, D * D, wsum + 3);
    finalize_ws_kernel<<<1, 64, 0, stream>>>(wsum, wscale, D * D, OKV * D, OKV * D, D * D);

    quantw_kernel<<<4096, 256, 0, stream>>>(wq, Wq8, D * D, wscale, 0);
    quantw_kernel<<<1024, 256, 0, stream>>>(wk, Wk8, OKV * D, wscale, 1);
    quantw_kernel<<<1024, 256, 0, stream>>>(wv, Wv8, OKV * D, wscale, 2);
    quantw_kernel<<<4096, 256, 0, stream>>>(wo, Wo8, D * D, wscale, 3);

    rmsq3_kernel<<<R, 256, 0, stream>>>(x, gq, gk, gv, Xq_q, Xq_k, Xq_v,
                                        xs + 0 * R, xs + 1 * R, xs + 2 * R);

    gemm_i8_mfma<128><<<dim3(D / 128, R / 128), 256, 0, stream>>>(Xq_q, Wq8, qb, xs + 0 * R, wscale, 0, D);
    gemm_i8_mfma<64><<<dim3(OKV / 64, R / 128), 256, 0, stream>>>(Xq_k, Wk8, kb, xs + 1 * R, wscale, 1, OKV);
    gemm_i8_mfma<64><<<dim3(OKV / 64, R / 128), 256, 0, stream>>>(Xq_v, Wv8, vb, xs + 2 * R, wscale, 2, OKV);

    {
        int totq = R * H * 32;
        rope_bf16_kernel<<<(totq + 255) / 256, 256, 0, stream>>>(qb, cs, sn, qhb, H, totq);
        int totk = R * KVH * 32;
        rope_bf16_kernel<<<(totk + 255) / 256, 256, 0, stream>>>(kb, cs, sn, khb, KVH, totk);
        vtrans_kernel<<<dim3(T / 64, B * KVH), 256, 0, stream>>>(vb, vtb);
    }

    attn_mfma_kernel<<<dim3(T / 128, H, B), 256, 0, stream>>>(qhb, khb, vtb, ab);

    rmsq_kernel<<<R, 256, 0, stream>>>(ab, go, Aq8, xs + 3 * R);
    gemm_i8_mfma<128><<<dim3(D / 128, R / 128), 256, 0, stream>>>(Aq8, Wo8, out, xs + 3 * R, wscale, 3, D);
}